// Round 4
// baseline (43.717 us; speedup 1.0000x reference)
//
#include <hip/hip_runtime.h>

#define DD 256
#define TQ 512
#define TK 1024
#define C2 2.88539008177792681472f   // 2*log2(e)

__device__ __forceinline__ float fexp2(float x){ return __builtin_amdgcn_exp2f(x); }
__device__ __forceinline__ float frcp (float x){ return __builtin_amdgcn_rcpf(x); }

// -------- proj: out[r][c] = exp2( C2 * sum_d X[r][d] * W[c][d] ) --------
// tile 32 rows x 16 cols, 1024 threads = 4 K-groups x 256 threads, 2x1 micro.
// grid (16, 48): by<16 -> query tiles (Eq), else key tiles (Ek).
__global__ __launch_bounds__(1024, 8) void proj_kernel(
    const float* __restrict__ query, const float* __restrict__ key,
    const float* __restrict__ Wq, const float* __restrict__ Wk,
    float* __restrict__ eqo, float* __restrict__ eko)
{
    __shared__ float smem[13312];
    float* Xs = smem;            // [256][34]: Xs[d*34 + r], r<32 (transposed)
    float* Ws = smem + 8704;     // [256][18]: Ws[d*18 + c], c<16
    float* red = smem;           // alias, used after sync

    int by = blockIdx.y;
    const float* X; const float* W; float* out;
    if (by < 16) { X = query; W = Wq; out = eqo; }
    else { by -= 16; X = key; W = Wk; out = eko; }
    const int r0 = by * 32, c0 = blockIdx.x * 16;
    const int tid = threadIdx.x;

    {
        int f = tid;
        #pragma unroll
        for (int rep = 0; rep < 2; ++rep, f += 1024) {
            int row = f & 31, d4 = (f >> 5) << 2;
            float4 xv = *(const float4*)&X[(r0 + row) * DD + d4];
            Xs[(d4 + 0) * 34 + row] = xv.x;
            Xs[(d4 + 1) * 34 + row] = xv.y;
            Xs[(d4 + 2) * 34 + row] = xv.z;
            Xs[(d4 + 3) * 34 + row] = xv.w;
        }
        int c = tid & 15, d4 = (tid >> 4) << 2;
        float4 wv = *(const float4*)&W[(c0 + c) * DD + d4];
        Ws[(d4 + 0) * 18 + c] = wv.x;
        Ws[(d4 + 1) * 18 + c] = wv.y;
        Ws[(d4 + 2) * 18 + c] = wv.z;
        Ws[(d4 + 3) * 18 + c] = wv.w;
    }
    __syncthreads();

    const int g = tid >> 8, t2 = tid & 255;
    const int cx = t2 & 15, ry = t2 >> 4;     // ry = row-pair index 0..15
    float a0 = 0.f, a1 = 0.f;
    const int dend = g * 64 + 64;
    #pragma unroll 4
    for (int d = g * 64; d < dend; ++d) {
        float2 xv = *(const float2*)&Xs[d * 34 + ry * 2];
        float  wv = Ws[d * 18 + cx];
        a0 = fmaf(xv.x, wv, a0);
        a1 = fmaf(xv.y, wv, a1);
    }
    __syncthreads();
    if (g > 0) {
        red[(g - 1) * 256 + t2]       = a0;
        red[768 + (g - 1) * 256 + t2] = a1;
    }
    __syncthreads();
    if (g == 0) {
        a0 += red[t2] + red[256 + t2] + red[512 + t2];
        a1 += red[768 + t2] + red[1024 + t2] + red[1280 + t2];
        out[(r0 + ry * 2 + 0) * DD + c0 + cx] = fexp2(C2 * a0);
        out[(r0 + ry * 2 + 1) * DD + c0 + cx] = fexp2(C2 * a1);
    }
}

// -------- scores: out[q][k] = vsum - 2 * sum_d v[d] / (Eq[q][d]*Ek[k][d] + 1) --------
// tile 32 q x 32 k, 1024 threads = 8 d-groups x 128 threads, 2q x 4k micro.
__global__ __launch_bounds__(1024, 8) void scores_kernel(
    const float* __restrict__ eqg, const float* __restrict__ ekg,
    const float* __restrict__ v, float* __restrict__ out)
{
    __shared__ float smem[17668];
    float* eq = smem;            // [256][34]: eq[d*34 + r], r<32
    float* ek = smem + 8704;     // [256][34]: ek[d*34 + c], c<32
    float* vs = smem + 17408;    // [256]
    // vsum at smem[17664]; reduction buffer aliases smem[0..8063] after loop

    const int qb = blockIdx.y, kb = blockIdx.x;
    const int tid = threadIdx.x;

    {
        int f = tid;
        #pragma unroll
        for (int rep = 0; rep < 2; ++rep, f += 1024) {
            int row = f & 31, d4 = (f >> 5) << 2;
            float4 qv = *(const float4*)&eqg[(qb * 32 + row) * DD + d4];
            eq[(d4 + 0) * 34 + row] = qv.x;
            eq[(d4 + 1) * 34 + row] = qv.y;
            eq[(d4 + 2) * 34 + row] = qv.z;
            eq[(d4 + 3) * 34 + row] = qv.w;
            float4 kv = *(const float4*)&ekg[(kb * 32 + row) * DD + d4];
            ek[(d4 + 0) * 34 + row] = kv.x;
            ek[(d4 + 1) * 34 + row] = kv.y;
            ek[(d4 + 2) * 34 + row] = kv.z;
            ek[(d4 + 3) * 34 + row] = kv.w;
        }
        if (tid < 64) {
            float4 vv = *(const float4*)&v[tid * 4];
            vs[tid * 4 + 0] = vv.x; vs[tid * 4 + 1] = vv.y;
            vs[tid * 4 + 2] = vv.z; vs[tid * 4 + 3] = vv.w;
            float s = vv.x + vv.y + vv.z + vv.w;
            #pragma unroll
            for (int m = 1; m < 64; m <<= 1) s += __shfl_xor(s, m);
            if (tid == 0) smem[17664] = s;
        }
    }
    __syncthreads();

    const int g = tid >> 7, t2 = tid & 127;   // 8 groups x 128 threads
    const int kq = t2 & 7, qp = t2 >> 3;      // kq: k-quad 0..7, qp: q-pair 0..15
    float a[8] = {0.f, 0.f, 0.f, 0.f, 0.f, 0.f, 0.f, 0.f};

    const int d0 = g * 32;
    #pragma unroll 4
    for (int d = d0; d < d0 + 32; ++d) {
        float2 q2 = *(const float2*)&eq[d * 34 + qp * 2];
        float4 k4 = *(const float4*)&ek[d * 34 + kq * 4];
        float  vd = vs[d];
        float x0 = fmaf(q2.x, k4.x, 1.f);
        float x1 = fmaf(q2.x, k4.y, 1.f);
        float x2 = fmaf(q2.x, k4.z, 1.f);
        float x3 = fmaf(q2.x, k4.w, 1.f);
        float y0 = fmaf(q2.y, k4.x, 1.f);
        float y1 = fmaf(q2.y, k4.y, 1.f);
        float y2 = fmaf(q2.y, k4.z, 1.f);
        float y3 = fmaf(q2.y, k4.w, 1.f);
        a[0] = fmaf(vd, frcp(x0), a[0]);
        a[1] = fmaf(vd, frcp(x1), a[1]);
        a[2] = fmaf(vd, frcp(x2), a[2]);
        a[3] = fmaf(vd, frcp(x3), a[3]);
        a[4] = fmaf(vd, frcp(y0), a[4]);
        a[5] = fmaf(vd, frcp(y1), a[5]);
        a[6] = fmaf(vd, frcp(y2), a[6]);
        a[7] = fmaf(vd, frcp(y3), a[7]);
    }

    __syncthreads();   // all reads of eq/ek done; safe to alias as reduction buf
    float* red = smem;
    if (g > 0) {
        int base = ((g - 1) * 128 + t2) * 9;   // stride 9: gcd(9,32)=1, conflict-free
        #pragma unroll
        for (int j = 0; j < 8; ++j) red[base + j] = a[j];
    }
    __syncthreads();
    if (g == 0) {
        #pragma unroll
        for (int i = 0; i < 7; ++i) {
            int base = (i * 128 + t2) * 9;
            #pragma unroll
            for (int j = 0; j < 8; ++j) a[j] += red[base + j];
        }
        float vsum = smem[17664];
        const int row = qb * 32 + qp * 2, col = kb * 32 + kq * 4;
        float4 s0 = make_float4(fmaf(-2.f, a[0], vsum), fmaf(-2.f, a[1], vsum),
                                fmaf(-2.f, a[2], vsum), fmaf(-2.f, a[3], vsum));
        float4 s1 = make_float4(fmaf(-2.f, a[4], vsum), fmaf(-2.f, a[5], vsum),
                                fmaf(-2.f, a[6], vsum), fmaf(-2.f, a[7], vsum));
        *(float4*)&out[row * TK + col]       = s0;
        *(float4*)&out[(row + 1) * TK + col] = s1;
    }
}

extern "C" void kernel_launch(void* const* d_in, const int* in_sizes, int n_in,
                              void* d_out, int out_size, void* d_ws, size_t ws_size,
                              hipStream_t stream) {
    const float* query = (const float*)d_in[0];   // [512,256]
    const float* key   = (const float*)d_in[1];   // [1024,256]
    // d_in[2] = value, unused by the reference
    const float* Wq    = (const float*)d_in[3];   // [256,256]
    const float* Wk    = (const float*)d_in[4];   // [256,256]
    const float* vw    = (const float*)d_in[5];   // [1,256]
    float* out = (float*)d_out;                   // [512,1024]

    float* eq = (float*)d_ws;                     // 512*256 f32
    float* ek = eq + TQ * DD;                     // 1024*256 f32

    proj_kernel<<<dim3(16, 48), 1024, 0, stream>>>(query, key, Wq, Wk, eq, ek);
    scores_kernel<<<dim3(TK / 32, TQ / 32), 1024, 0, stream>>>(eq, ek, vw, out);
}

// Round 5
// 35.304 us; speedup vs baseline: 1.2383x; 1.2383x over previous
//
#include <hip/hip_runtime.h>

#define DD 256
#define TQ 512
#define TK 1024
#define C2 2.88539008177792681472f   // 2*log2(e)

__device__ __forceinline__ float fexp2(float x){ return __builtin_amdgcn_exp2f(x); }
__device__ __forceinline__ float frcp (float x){ return __builtin_amdgcn_rcpf(x); }

// -------- proj: out[r][c] = exp2( C2 * sum_d X[r][d] * W[c][d] ) --------
// tile 32 rows x 32 cols, 1024 threads = 4 d-groups x 256 threads, 2x2 micro.
// grid (8, 48): by<16 -> query tiles (Eq), else key tiles (Ek).
__global__ __launch_bounds__(1024, 8) void proj_kernel(
    const float* __restrict__ query, const float* __restrict__ key,
    const float* __restrict__ Wq, const float* __restrict__ Wk,
    float* __restrict__ eqo, float* __restrict__ eko)
{
    __shared__ float smem[17408];
    float* Xs = smem;            // [256][34]: Xs[d*34 + r], r<32 (transposed)
    float* Ws = smem + 8704;     // [256][34]: Ws[d*34 + c], c<32
    float* red = smem;           // alias, used after sync

    int by = blockIdx.y;
    const float* X; const float* W; float* out;
    if (by < 16) { X = query; W = Wq; out = eqo; }
    else { by -= 16; X = key; W = Wk; out = eko; }
    const int r0 = by * 32, c0 = blockIdx.x * 32;
    const int tid = threadIdx.x;

    {
        int f = tid;
        #pragma unroll
        for (int rep = 0; rep < 2; ++rep, f += 1024) {
            int row = f & 31, d4 = (f >> 5) << 2;
            float4 xv = *(const float4*)&X[(r0 + row) * DD + d4];
            Xs[(d4 + 0) * 34 + row] = xv.x;
            Xs[(d4 + 1) * 34 + row] = xv.y;
            Xs[(d4 + 2) * 34 + row] = xv.z;
            Xs[(d4 + 3) * 34 + row] = xv.w;
            float4 wv = *(const float4*)&W[(c0 + row) * DD + d4];
            Ws[(d4 + 0) * 34 + row] = wv.x;
            Ws[(d4 + 1) * 34 + row] = wv.y;
            Ws[(d4 + 2) * 34 + row] = wv.z;
            Ws[(d4 + 3) * 34 + row] = wv.w;
        }
    }
    __syncthreads();

    const int g = tid >> 8, t2 = tid & 255;
    const int cx2 = (t2 & 15) * 2, ry2 = (t2 >> 4) * 2;
    float a00 = 0.f, a01 = 0.f, a10 = 0.f, a11 = 0.f;
    const int dend = g * 64 + 64;
    #pragma unroll 4
    for (int d = g * 64; d < dend; ++d) {
        float2 xv = *(const float2*)&Xs[d * 34 + ry2];
        float2 wv = *(const float2*)&Ws[d * 34 + cx2];
        a00 = fmaf(xv.x, wv.x, a00);
        a01 = fmaf(xv.x, wv.y, a01);
        a10 = fmaf(xv.y, wv.x, a10);
        a11 = fmaf(xv.y, wv.y, a11);
    }
    __syncthreads();
    if (g > 0) {
        *(float4*)&red[((g - 1) * 256 + t2) * 4] = make_float4(a00, a01, a10, a11);
    }
    __syncthreads();
    if (g == 0) {
        #pragma unroll
        for (int i = 0; i < 3; ++i) {
            float4 p = *(float4*)&red[(i * 256 + t2) * 4];
            a00 += p.x; a01 += p.y; a10 += p.z; a11 += p.w;
        }
        float2 s0 = make_float2(fexp2(C2 * a00), fexp2(C2 * a01));
        float2 s1 = make_float2(fexp2(C2 * a10), fexp2(C2 * a11));
        *(float2*)&out[(r0 + ry2 + 0) * DD + c0 + cx2] = s0;
        *(float2*)&out[(r0 + ry2 + 1) * DD + c0 + cx2] = s1;
    }
}

// -------- scores: out[q][k] = vsum - 2 * sum_d v[d] / (Eq[q][d]*Ek[k][d] + 1) --------
// tile 32 q x 32 k, 512 threads = 8 one-wave d-groups, 4x4 micro.
// LDS stride 36: 36d + 4*idx is 0 mod 4 -> every float4 read is 16B-aligned;
// banks (4d + 4qp + row)%32 conflict-free.
__global__ __launch_bounds__(512, 4) void scores_kernel(
    const float* __restrict__ eqg, const float* __restrict__ ekg,
    const float* __restrict__ v, float* __restrict__ out)
{
    __shared__ float smem[18690];
    float* eq = smem;            // [256][36]: eq[d*36 + r], r<32
    float* ek = smem + 9216;     // [256][36]: ek[d*36 + c], c<32
    float* vs = smem + 18432;    // [256]
    // vsum at smem[18688]; reduction buffer aliases smem[0..8959] after loop

    const int qb = blockIdx.y, kb = blockIdx.x;
    const int tid = threadIdx.x;

    {
        int f = tid;
        #pragma unroll
        for (int rep = 0; rep < 4; ++rep, f += 512) {
            int row = f & 31, d4 = (f >> 5) << 2;
            float4 qv = *(const float4*)&eqg[(qb * 32 + row) * DD + d4];
            eq[(d4 + 0) * 36 + row] = qv.x;
            eq[(d4 + 1) * 36 + row] = qv.y;
            eq[(d4 + 2) * 36 + row] = qv.z;
            eq[(d4 + 3) * 36 + row] = qv.w;
            float4 kv = *(const float4*)&ekg[(kb * 32 + row) * DD + d4];
            ek[(d4 + 0) * 36 + row] = kv.x;
            ek[(d4 + 1) * 36 + row] = kv.y;
            ek[(d4 + 2) * 36 + row] = kv.z;
            ek[(d4 + 3) * 36 + row] = kv.w;
        }
        if (tid < 64) {
            float4 vv = *(const float4*)&v[tid * 4];
            vs[tid * 4 + 0] = vv.x; vs[tid * 4 + 1] = vv.y;
            vs[tid * 4 + 2] = vv.z; vs[tid * 4 + 3] = vv.w;
            float s = vv.x + vv.y + vv.z + vv.w;
            #pragma unroll
            for (int m = 1; m < 64; m <<= 1) s += __shfl_xor(s, m);
            if (tid == 0) smem[18688] = s;
        }
    }
    __syncthreads();

    const int g = tid >> 6, t = tid & 63;    // 8 groups, each one full wave
    const int qp4 = (t >> 3) * 4, kq4 = (t & 7) * 4;
    float a[4][4] = {{0.f,0.f,0.f,0.f},{0.f,0.f,0.f,0.f},
                     {0.f,0.f,0.f,0.f},{0.f,0.f,0.f,0.f}};

    const int d0 = g * 32;
    #pragma unroll 2
    for (int d = d0; d < d0 + 32; ++d) {
        float4 q4 = *(const float4*)&eq[d * 36 + qp4];
        float4 k4 = *(const float4*)&ek[d * 36 + kq4];
        float  vd = vs[d];
        float qq[4] = {q4.x, q4.y, q4.z, q4.w};
        float kk[4] = {k4.x, k4.y, k4.z, k4.w};
        #pragma unroll
        for (int i = 0; i < 4; ++i)
            #pragma unroll
            for (int j = 0; j < 4; ++j)
                a[i][j] = fmaf(vd, frcp(fmaf(qq[i], kk[j], 1.f)), a[i][j]);
    }

    __syncthreads();   // all reads of eq/ek done; safe to alias as reduction buf
    float* red = smem;
    if (g > 0) {
        int base = ((g - 1) * 64 + t) * 20;   // 20 floats: 16B-aligned, 2-way banks (free)
        #pragma unroll
        for (int i = 0; i < 4; ++i)
            *(float4*)&red[base + i * 4] = make_float4(a[i][0], a[i][1], a[i][2], a[i][3]);
    }
    __syncthreads();
    if (g == 0) {
        #pragma unroll
        for (int p = 0; p < 7; ++p) {
            int base = (p * 64 + t) * 20;
            #pragma unroll
            for (int i = 0; i < 4; ++i) {
                float4 r4 = *(float4*)&red[base + i * 4];
                a[i][0] += r4.x; a[i][1] += r4.y; a[i][2] += r4.z; a[i][3] += r4.w;
            }
        }
        float vsum = smem[18688];
        const int row0 = qb * 32 + qp4, col = kb * 32 + kq4;
        #pragma unroll
        for (int i = 0; i < 4; ++i) {
            float4 s = make_float4(fmaf(-2.f, a[i][0], vsum), fmaf(-2.f, a[i][1], vsum),
                                   fmaf(-2.f, a[i][2], vsum), fmaf(-2.f, a[i][3], vsum));
            *(float4*)&out[(row0 + i) * TK + col] = s;
        }
    }
}

extern "C" void kernel_launch(void* const* d_in, const int* in_sizes, int n_in,
                              void* d_out, int out_size, void* d_ws, size_t ws_size,
                              hipStream_t stream) {
    const float* query = (const float*)d_in[0];   // [512,256]
    const float* key   = (const float*)d_in[1];   // [1024,256]
    // d_in[2] = value, unused by the reference
    const float* Wq    = (const float*)d_in[3];   // [256,256]
    const float* Wk    = (const float*)d_in[4];   // [256,256]
    const float* vw    = (const float*)d_in[5];   // [1,256]
    float* out = (float*)d_out;                   // [512,1024]

    float* eq = (float*)d_ws;                     // 512*256 f32
    float* ek = eq + TQ * DD;                     // 1024*256 f32

    proj_kernel<<<dim3(8, 48), 1024, 0, stream>>>(query, key, Wq, Wk, eq, ek);
    scores_kernel<<<dim3(TK / 32, TQ / 32), 512, 0, stream>>>(eq, ek, vw, out);
}

// Round 6
// 32.774 us; speedup vs baseline: 1.3339x; 1.0772x over previous
//
#include <hip/hip_runtime.h>

#define DD 256
#define TQ 512
#define TK 1024
#define C2 2.88539008177792681472f   // 2*log2(e)

__device__ __forceinline__ float fexp2(float x){ return __builtin_amdgcn_exp2f(x); }
__device__ __forceinline__ float frcp (float x){ return __builtin_amdgcn_rcpf(x); }

// -------- proj: out[r][c] = exp2( C2 * sum_d X[r][d] * W[c][d] ) --------
// tile 32 rows x 32 cols, 1024 threads = 4 d-groups x 256 threads, 2x2 micro.
// grid (8, 48): by<16 -> query tiles (Eq), else key tiles (Ek).  (unchanged from R5)
__global__ __launch_bounds__(1024, 8) void proj_kernel(
    const float* __restrict__ query, const float* __restrict__ key,
    const float* __restrict__ Wq, const float* __restrict__ Wk,
    float* __restrict__ eqo, float* __restrict__ eko)
{
    __shared__ float smem[17408];
    float* Xs = smem;            // [256][34]: Xs[d*34 + r], r<32 (transposed)
    float* Ws = smem + 8704;     // [256][34]: Ws[d*34 + c], c<32
    float* red = smem;           // alias, used after sync

    int by = blockIdx.y;
    const float* X; const float* W; float* out;
    if (by < 16) { X = query; W = Wq; out = eqo; }
    else { by -= 16; X = key; W = Wk; out = eko; }
    const int r0 = by * 32, c0 = blockIdx.x * 32;
    const int tid = threadIdx.x;

    {
        int f = tid;
        #pragma unroll
        for (int rep = 0; rep < 2; ++rep, f += 1024) {
            int row = f & 31, d4 = (f >> 5) << 2;
            float4 xv = *(const float4*)&X[(r0 + row) * DD + d4];
            Xs[(d4 + 0) * 34 + row] = xv.x;
            Xs[(d4 + 1) * 34 + row] = xv.y;
            Xs[(d4 + 2) * 34 + row] = xv.z;
            Xs[(d4 + 3) * 34 + row] = xv.w;
            float4 wv = *(const float4*)&W[(c0 + row) * DD + d4];
            Ws[(d4 + 0) * 34 + row] = wv.x;
            Ws[(d4 + 1) * 34 + row] = wv.y;
            Ws[(d4 + 2) * 34 + row] = wv.z;
            Ws[(d4 + 3) * 34 + row] = wv.w;
        }
    }
    __syncthreads();

    const int g = tid >> 8, t2 = tid & 255;
    const int cx2 = (t2 & 15) * 2, ry2 = (t2 >> 4) * 2;
    float a00 = 0.f, a01 = 0.f, a10 = 0.f, a11 = 0.f;
    const int dend = g * 64 + 64;
    #pragma unroll 4
    for (int d = g * 64; d < dend; ++d) {
        float2 xv = *(const float2*)&Xs[d * 34 + ry2];
        float2 wv = *(const float2*)&Ws[d * 34 + cx2];
        a00 = fmaf(xv.x, wv.x, a00);
        a01 = fmaf(xv.x, wv.y, a01);
        a10 = fmaf(xv.y, wv.x, a10);
        a11 = fmaf(xv.y, wv.y, a11);
    }
    __syncthreads();
    if (g > 0) {
        *(float4*)&red[((g - 1) * 256 + t2) * 4] = make_float4(a00, a01, a10, a11);
    }
    __syncthreads();
    if (g == 0) {
        #pragma unroll
        for (int i = 0; i < 3; ++i) {
            float4 p = *(float4*)&red[(i * 256 + t2) * 4];
            a00 += p.x; a01 += p.y; a10 += p.z; a11 += p.w;
        }
        float2 s0 = make_float2(fexp2(C2 * a00), fexp2(C2 * a01));
        float2 s1 = make_float2(fexp2(C2 * a10), fexp2(C2 * a11));
        *(float2*)&out[(r0 + ry2 + 0) * DD + c0 + cx2] = s0;
        *(float2*)&out[(r0 + ry2 + 1) * DD + c0 + cx2] = s1;
    }
}

// -------- scores: out[q][k] = vsum - 2 * sum_d v[d] / (Eq[q][d]*Ek[k][d] + 1) --------
// tile 32 q x 32 k, 512 threads = 8 one-wave d-groups, 4x4 micro.
// 4-term common denominator: 1 rcp per 4 d-terms.
// LDS layout [row][260]: d-contiguous rows; b128 reads conflict-free
// (8 distinct rows x 4 banks = 32 banks, 8-lane broadcast each).
__global__ __launch_bounds__(512, 4) void scores_kernel(
    const float* __restrict__ eqg, const float* __restrict__ ekg,
    const float* __restrict__ v, float* __restrict__ out)
{
    __shared__ float smem[16897];
    float* eq = smem;            // [32][260]: eq[r*260 + d], r<32
    float* ek = smem + 8320;     // [32][260]: ek[c*260 + d], c<32
    float* vs = smem + 16640;    // [256]
    // vsum at smem[16896]; reduction buffer aliases smem[0..8959] after loop

    const int qb = blockIdx.y, kb = blockIdx.x;
    const int tid = threadIdx.x;

    {
        int f = tid;
        #pragma unroll
        for (int rep = 0; rep < 4; ++rep, f += 512) {
            int row = f & 31, d4 = (f >> 5) << 2;
            float4 qv = *(const float4*)&eqg[(qb * 32 + row) * DD + d4];
            *(float4*)&eq[row * 260 + d4] = qv;
            float4 kv = *(const float4*)&ekg[(kb * 32 + row) * DD + d4];
            *(float4*)&ek[row * 260 + d4] = kv;
        }
        if (tid < 64) {
            float4 vv = *(const float4*)&v[tid * 4];
            *(float4*)&vs[tid * 4] = vv;
            float s = vv.x + vv.y + vv.z + vv.w;
            #pragma unroll
            for (int m = 1; m < 64; m <<= 1) s += __shfl_xor(s, m);
            if (tid == 0) smem[16896] = s;
        }
    }
    __syncthreads();

    const int g = tid >> 6, t = tid & 63;    // 8 groups, each one full wave
    const int qp4 = (t >> 3) * 4, kq4 = (t & 7) * 4;
    float a[4][4] = {{0.f,0.f,0.f,0.f},{0.f,0.f,0.f,0.f},
                     {0.f,0.f,0.f,0.f},{0.f,0.f,0.f,0.f}};

    const int dbase = g * 32;
    #pragma unroll 2
    for (int s = 0; s < 8; ++s) {
        const int d0 = dbase + s * 4;
        float4 v4 = *(const float4*)&vs[d0];
        float4 Q[4], K[4];
        #pragma unroll
        for (int i = 0; i < 4; ++i) Q[i] = *(const float4*)&eq[(qp4 + i) * 260 + d0];
        #pragma unroll
        for (int j = 0; j < 4; ++j) K[j] = *(const float4*)&ek[(kq4 + j) * 260 + d0];
        #pragma unroll
        for (int i = 0; i < 4; ++i) {
            #pragma unroll
            for (int j = 0; j < 4; ++j) {
                float t0 = fmaf(Q[i].x, K[j].x, 1.f);
                float t1 = fmaf(Q[i].y, K[j].y, 1.f);
                float t2 = fmaf(Q[i].z, K[j].z, 1.f);
                float t3 = fmaf(Q[i].w, K[j].w, 1.f);
                float A  = t0 * t1;
                float B  = t2 * t3;
                float den = A * B;
                float n01 = fmaf(v4.x, t1, v4.y * t0);
                float n23 = fmaf(v4.z, t3, v4.w * t2);
                float num = fmaf(n01, B, n23 * A);
                a[i][j] = fmaf(num, frcp(den), a[i][j]);
            }
        }
    }

    __syncthreads();   // all reads of eq/ek done; safe to alias as reduction buf
    float* red = smem;
    if (g > 0) {
        int base = ((g - 1) * 64 + t) * 20;   // 20 floats: 16B-aligned, 2-way banks (free)
        #pragma unroll
        for (int i = 0; i < 4; ++i)
            *(float4*)&red[base + i * 4] = make_float4(a[i][0], a[i][1], a[i][2], a[i][3]);
    }
    __syncthreads();
    if (g == 0) {
        #pragma unroll
        for (int p = 0; p < 7; ++p) {
            int base = (p * 64 + t) * 20;
            #pragma unroll
            for (int i = 0; i < 4; ++i) {
                float4 r4 = *(float4*)&red[base + i * 4];
                a[i][0] += r4.x; a[i][1] += r4.y; a[i][2] += r4.z; a[i][3] += r4.w;
            }
        }
        float vsum = smem[16896];
        const int row0 = qb * 32 + qp4, col = kb * 32 + kq4;
        #pragma unroll
        for (int i = 0; i < 4; ++i) {
            float4 s = make_float4(fmaf(-2.f, a[i][0], vsum), fmaf(-2.f, a[i][1], vsum),
                                   fmaf(-2.f, a[i][2], vsum), fmaf(-2.f, a[i][3], vsum));
            *(float4*)&out[(row0 + i) * TK + col] = s;
        }
    }
}

extern "C" void kernel_launch(void* const* d_in, const int* in_sizes, int n_in,
                              void* d_out, int out_size, void* d_ws, size_t ws_size,
                              hipStream_t stream) {
    const float* query = (const float*)d_in[0];   // [512,256]
    const float* key   = (const float*)d_in[1];   // [1024,256]
    // d_in[2] = value, unused by the reference
    const float* Wq    = (const float*)d_in[3];   // [256,256]
    const float* Wk    = (const float*)d_in[4];   // [256,256]
    const float* vw    = (const float*)d_in[5];   // [1,256]
    float* out = (float*)d_out;                   // [512,1024]

    float* eq = (float*)d_ws;                     // 512*256 f32
    float* ek = eq + TQ * DD;                     // 1024*256 f32

    proj_kernel<<<dim3(8, 48), 1024, 0, stream>>>(query, key, Wq, Wk, eq, ek);
    scores_kernel<<<dim3(TK / 32, TQ / 32), 512, 0, stream>>>(eq, ek, vw, out);
}

// Round 7
// 29.267 us; speedup vs baseline: 1.4938x; 1.1199x over previous
//
#include <hip/hip_runtime.h>

#define DD 256
#define TQ 512
#define TK 1024
#define C2 2.88539008177792681472f   // 2*log2(e)

__device__ __forceinline__ float fexp2(float x){ return __builtin_amdgcn_exp2f(x); }
__device__ __forceinline__ float frcp (float x){ return __builtin_amdgcn_rcpf(x); }

// -------- proj: out[r][c] = exp2( C2 * sum_d X[r][d] * W[c][d] ) --------
// tile 32 rows x 32 cols, 512 threads = 8 one-wave d-groups, 4x4 micro.
// d-major LDS stride 36: float4 reads at (36d + 4*grp) cover all 32 banks, conflict-free.
// grid (8, 48): by<16 -> query tiles (Eq), else key tiles (Ek).
__global__ __launch_bounds__(512, 4) void proj_kernel(
    const float* __restrict__ query, const float* __restrict__ key,
    const float* __restrict__ Wq, const float* __restrict__ Wk,
    float* __restrict__ eqo, float* __restrict__ eko)
{
    __shared__ float smem[18432];
    float* Xs = smem;            // [256][36]: Xs[d*36 + r], r<32
    float* Ws = smem + 9216;     // [256][36]: Ws[d*36 + c], c<32

    int by = blockIdx.y;
    const float* X; const float* W; float* out;
    if (by < 16) { X = query; W = Wq; out = eqo; }
    else { by -= 16; X = key; W = Wk; out = eko; }
    const int r0 = by * 32, c0 = blockIdx.x * 32;
    const int tid = threadIdx.x;

    {
        int f = tid;
        #pragma unroll
        for (int rep = 0; rep < 4; ++rep, f += 512) {
            int row = f & 31, d4 = (f >> 5) << 2;
            float4 xv = *(const float4*)&X[(r0 + row) * DD + d4];
            Xs[(d4 + 0) * 36 + row] = xv.x;
            Xs[(d4 + 1) * 36 + row] = xv.y;
            Xs[(d4 + 2) * 36 + row] = xv.z;
            Xs[(d4 + 3) * 36 + row] = xv.w;
            float4 wv = *(const float4*)&W[(c0 + row) * DD + d4];
            Ws[(d4 + 0) * 36 + row] = wv.x;
            Ws[(d4 + 1) * 36 + row] = wv.y;
            Ws[(d4 + 2) * 36 + row] = wv.z;
            Ws[(d4 + 3) * 36 + row] = wv.w;
        }
    }
    __syncthreads();

    const int g = tid >> 6, t = tid & 63;    // 8 groups, each one full wave
    const int ry4 = (t >> 3) * 4, cx4 = (t & 7) * 4;
    float a[4][4] = {{0.f,0.f,0.f,0.f},{0.f,0.f,0.f,0.f},
                     {0.f,0.f,0.f,0.f},{0.f,0.f,0.f,0.f}};

    const int dbase = g * 32;
    #pragma unroll 4
    for (int d = dbase; d < dbase + 32; ++d) {
        float4 x4 = *(const float4*)&Xs[d * 36 + ry4];
        float4 w4 = *(const float4*)&Ws[d * 36 + cx4];
        float xx[4] = {x4.x, x4.y, x4.z, x4.w};
        float ww[4] = {w4.x, w4.y, w4.z, w4.w};
        #pragma unroll
        for (int i = 0; i < 4; ++i)
            #pragma unroll
            for (int j = 0; j < 4; ++j)
                a[i][j] = fmaf(xx[i], ww[j], a[i][j]);
    }

    __syncthreads();   // all reads of Xs/Ws done; safe to alias as reduction buf
    float* red = smem;
    if (g > 0) {
        int base = ((g - 1) * 64 + t) * 20;   // 16B-aligned, 2-way banks (free)
        #pragma unroll
        for (int i = 0; i < 4; ++i)
            *(float4*)&red[base + i * 4] = make_float4(a[i][0], a[i][1], a[i][2], a[i][3]);
    }
    __syncthreads();
    if (g == 0) {
        #pragma unroll
        for (int p = 0; p < 7; ++p) {
            int base = (p * 64 + t) * 20;
            #pragma unroll
            for (int i = 0; i < 4; ++i) {
                float4 r4 = *(float4*)&red[base + i * 4];
                a[i][0] += r4.x; a[i][1] += r4.y; a[i][2] += r4.z; a[i][3] += r4.w;
            }
        }
        #pragma unroll
        for (int i = 0; i < 4; ++i) {
            float4 s = make_float4(fexp2(C2 * a[i][0]), fexp2(C2 * a[i][1]),
                                   fexp2(C2 * a[i][2]), fexp2(C2 * a[i][3]));
            *(float4*)&out[(r0 + ry4 + i) * DD + c0 + cx4] = s;
        }
    }
}

// -------- scores: out[q][k] = vsum - 2 * sum_d v[d] / (Eq[q][d]*Ek[k][d] + 1) --------
// tile 32 q x 32 k, 512 threads = 8 one-wave d-groups, 4x4 micro.
// 4-term common denominator: 1 rcp per 4 d-terms.
// d-major LDS stride 36 (conflict-free b128 reads, 8-lane broadcast).
__global__ __launch_bounds__(512, 4) void scores_kernel(
    const float* __restrict__ eqg, const float* __restrict__ ekg,
    const float* __restrict__ v, float* __restrict__ out)
{
    __shared__ float smem[18690];
    float* eq = smem;            // [256][36]: eq[d*36 + r], r<32
    float* ek = smem + 9216;     // [256][36]: ek[d*36 + c], c<32
    float* vs = smem + 18432;    // [256]
    // vsum at smem[18688]; reduction buffer aliases smem[0..8959] after loop

    const int qb = blockIdx.y, kb = blockIdx.x;
    const int tid = threadIdx.x;

    {
        int f = tid;
        #pragma unroll
        for (int rep = 0; rep < 4; ++rep, f += 512) {
            int row = f & 31, d4 = (f >> 5) << 2;
            float4 qv = *(const float4*)&eqg[(qb * 32 + row) * DD + d4];
            eq[(d4 + 0) * 36 + row] = qv.x;
            eq[(d4 + 1) * 36 + row] = qv.y;
            eq[(d4 + 2) * 36 + row] = qv.z;
            eq[(d4 + 3) * 36 + row] = qv.w;
            float4 kv = *(const float4*)&ekg[(kb * 32 + row) * DD + d4];
            ek[(d4 + 0) * 36 + row] = kv.x;
            ek[(d4 + 1) * 36 + row] = kv.y;
            ek[(d4 + 2) * 36 + row] = kv.z;
            ek[(d4 + 3) * 36 + row] = kv.w;
        }
        if (tid < 64) {
            float4 vv = *(const float4*)&v[tid * 4];
            *(float4*)&vs[tid * 4] = vv;
            float s = vv.x + vv.y + vv.z + vv.w;
            #pragma unroll
            for (int m = 1; m < 64; m <<= 1) s += __shfl_xor(s, m);
            if (tid == 0) smem[18688] = s;
        }
    }
    __syncthreads();

    const int g = tid >> 6, t = tid & 63;    // 8 groups, each one full wave
    const int qp4 = (t >> 3) * 4, kq4 = (t & 7) * 4;
    float a[4][4] = {{0.f,0.f,0.f,0.f},{0.f,0.f,0.f,0.f},
                     {0.f,0.f,0.f,0.f},{0.f,0.f,0.f,0.f}};

    const int dbase = g * 32;
    #pragma unroll 2
    for (int s = 0; s < 8; ++s) {
        const int d0 = dbase + s * 4;
        float4 v4 = *(const float4*)&vs[d0];
        float Qr[4][4], Kr[4][4];             // [di][q/k idx], all-constant indexing
        #pragma unroll
        for (int di = 0; di < 4; ++di) {
            float4 q4 = *(const float4*)&eq[(d0 + di) * 36 + qp4];
            Qr[di][0] = q4.x; Qr[di][1] = q4.y; Qr[di][2] = q4.z; Qr[di][3] = q4.w;
            float4 k4 = *(const float4*)&ek[(d0 + di) * 36 + kq4];
            Kr[di][0] = k4.x; Kr[di][1] = k4.y; Kr[di][2] = k4.z; Kr[di][3] = k4.w;
        }
        #pragma unroll
        for (int i = 0; i < 4; ++i) {
            #pragma unroll
            for (int j = 0; j < 4; ++j) {
                float t0 = fmaf(Qr[0][i], Kr[0][j], 1.f);
                float t1 = fmaf(Qr[1][i], Kr[1][j], 1.f);
                float t2 = fmaf(Qr[2][i], Kr[2][j], 1.f);
                float t3 = fmaf(Qr[3][i], Kr[3][j], 1.f);
                float A  = t0 * t1;
                float B  = t2 * t3;
                float den = A * B;
                float n01 = fmaf(v4.x, t1, v4.y * t0);
                float n23 = fmaf(v4.z, t3, v4.w * t2);
                float num = fmaf(n01, B, n23 * A);
                a[i][j] = fmaf(num, frcp(den), a[i][j]);
            }
        }
    }

    __syncthreads();   // all reads of eq/ek done; safe to alias as reduction buf
    float* red = smem;
    if (g > 0) {
        int base = ((g - 1) * 64 + t) * 20;   // 16B-aligned, 2-way banks (free)
        #pragma unroll
        for (int i = 0; i < 4; ++i)
            *(float4*)&red[base + i * 4] = make_float4(a[i][0], a[i][1], a[i][2], a[i][3]);
    }
    __syncthreads();
    if (g == 0) {
        #pragma unroll
        for (int p = 0; p < 7; ++p) {
            int base = (p * 64 + t) * 20;
            #pragma unroll
            for (int i = 0; i < 4; ++i) {
                float4 r4 = *(float4*)&red[base + i * 4];
                a[i][0] += r4.x; a[i][1] += r4.y; a[i][2] += r4.z; a[i][3] += r4.w;
            }
        }
        float vsum = smem[18688];
        const int row0 = qb * 32 + qp4, col = kb * 32 + kq4;
        #pragma unroll
        for (int i = 0; i < 4; ++i) {
            float4 s = make_float4(fmaf(-2.f, a[i][0], vsum), fmaf(-2.f, a[i][1], vsum),
                                   fmaf(-2.f, a[i][2], vsum), fmaf(-2.f, a[i][3], vsum));
            *(float4*)&out[(row0 + i) * TK + col] = s;
        }
    }
}

extern "C" void kernel_launch(void* const* d_in, const int* in_sizes, int n_in,
                              void* d_out, int out_size, void* d_ws, size_t ws_size,
                              hipStream_t stream) {
    const float* query = (const float*)d_in[0];   // [512,256]
    const float* key   = (const float*)d_in[1];   // [1024,256]
    // d_in[2] = value, unused by the reference
    const float* Wq    = (const float*)d_in[3];   // [256,256]
    const float* Wk    = (const float*)d_in[4];   // [256,256]
    const float* vw    = (const float*)d_in[5];   // [1,256]
    float* out = (float*)d_out;                   // [512,1024]

    float* eq = (float*)d_ws;                     // 512*256 f32
    float* ek = eq + TQ * DD;                     // 1024*256 f32

    proj_kernel<<<dim3(8, 48), 512, 0, stream>>>(query, key, Wq, Wk, eq, ek);
    scores_kernel<<<dim3(TK / 32, TQ / 32), 512, 0, stream>>>(eq, ek, vw, out);
}